// Round 10
// baseline (70.915 us; speedup 1.0000x reference)
//
#include <hip/hip_runtime.h>

// FUME epipolar translation, fp32 in/out. B from in_sizes[3]; C,H,W = 4,128,128.
//
// R10: compact lane footprint. Both residual costs in fume scale with the
// geometric diameter of the 64-lane footprint: L1-line span per load
// (strip 64x1: |du/dx|*64 -> tile 8x8: (|du/dx|+|du/dy|)*8) and the
// wave-union k-interval length. Lanes now map to an 8x8 (x,y) tile
// (lx=tx&7, ly=tx>>3); the block's 8 waves cover the SAME tile and split
// its k-interval as before (identical lanes across waves -> identical
// union -> consistent split). Per-pixel math, mask decisions, and the
// 8-way reduction order are bit-identical to R9; only lane->pixel
// assignment changes. Grid (16,16,B) x 512 thr = 8192 waves.
//
// Workspace (16B entries = {half2(v[ch][u],v[ch][u+1])}ch=0..3):
//   horiz cube at entry ofs b*32768:        row r=x, col u=y : taps img[ch][u][x], img[ch][u+1][x]
//   vert  cube at entry ofs b*32768+16384:  row r=y, col u=x : taps img[ch][r][u], img[ch][r][u+1]
// (tap u+1 clamped at the image edge; entry col 127 is never read: i0<=126.)

#define CC 4
#define HH 128
#define WW 128

typedef _Float16 h2 __attribute__((ext_vector_type(2)));

__global__ void __launch_bounds__(256) fume_stage(
        const float* __restrict__ img, float4* __restrict__ ws) {
    __shared__ float tile[4][17][17];
    int x0 = blockIdx.x * 16, y0 = blockIdx.y * 16, b = blockIdx.z;
    int tx = threadIdx.x, ty = threadIdx.y;   // 16x16
    int id = ty * 16 + tx;
    const float* src = img + (size_t)b * CC * HH * WW;

    #pragma unroll
    for (int ch = 0; ch < 4; ++ch) {
        #pragma unroll
        for (int e = 0; e < 2; ++e) {
            int idx = id + e * 256;
            if (idx < 289) {
                int i = idx / 17, j = idx % 17;
                int r = min(y0 + i, HH - 1);
                int c = min(x0 + j, WW - 1);
                tile[ch][i][j] = src[(ch * HH + r) * WW + c];
            }
        }
    }
    __syncthreads();

    float4* base_h = ws + (size_t)b * 32768;
    float4* base_v = base_h + 16384;

    // vert entry: k = y0+ty, u = x0+tx : taps tile[ch][ty][tx], tile[ch][ty][tx+1]
    {
        h2 p0 = { (_Float16)tile[0][ty][tx], (_Float16)tile[0][ty][tx + 1] };
        h2 p1 = { (_Float16)tile[1][ty][tx], (_Float16)tile[1][ty][tx + 1] };
        h2 p2 = { (_Float16)tile[2][ty][tx], (_Float16)tile[2][ty][tx + 1] };
        h2 p3 = { (_Float16)tile[3][ty][tx], (_Float16)tile[3][ty][tx + 1] };
        float4 e = make_float4(__builtin_bit_cast(float, p0),
                               __builtin_bit_cast(float, p1),
                               __builtin_bit_cast(float, p2),
                               __builtin_bit_cast(float, p3));
        base_v[(y0 + ty) * WW + (x0 + tx)] = e;
    }
    // horiz entry: r = x0+ty, u = y0+tx : taps tile[ch][tx][ty], tile[ch][tx+1][ty]
    {
        h2 p0 = { (_Float16)tile[0][tx][ty], (_Float16)tile[0][tx + 1][ty] };
        h2 p1 = { (_Float16)tile[1][tx][ty], (_Float16)tile[1][tx + 1][ty] };
        h2 p2 = { (_Float16)tile[2][tx][ty], (_Float16)tile[2][tx + 1][ty] };
        h2 p3 = { (_Float16)tile[3][tx][ty], (_Float16)tile[3][tx + 1][ty] };
        float4 e = make_float4(__builtin_bit_cast(float, p0),
                               __builtin_bit_cast(float, p1),
                               __builtin_bit_cast(float, p2),
                               __builtin_bit_cast(float, p3));
        base_h[(x0 + ty) * HH + (y0 + tx)] = e;
    }
}

__global__ void __launch_bounds__(512) fume_kernel(
        const float4* __restrict__ cubes,
        const float* __restrict__ F,
        const float* __restrict__ dsf,
        float* __restrict__ out) {
    int tx  = threadIdx.x;               // 0..63 : lane -> (lx,ly) in 8x8 tile
    int seg = threadIdx.y;               // 0..7  : k-segment (wave id)
    int lx = tx & 7, ly = tx >> 3;
    int x = blockIdx.x * 8 + lx;
    int y = blockIdx.y * 8 + ly;
    int b = blockIdx.z;

    float d = dsf[b];
    float F00 = F[0], F01 = F[1], F02 = F[2];
    float F10 = F[3], F11 = F[4], F12 = F[5];
    float F20 = F[6], F21 = F[7], F22 = F[8];

    // Exact reference op order (no fma contraction).
    float px = __fmul_rn((float)x, d);
    float py = __fmul_rn((float)y, d);
    float av = __fadd_rn(__fadd_rn(__fmul_rn(F00, px), __fmul_rn(F01, py)), F02);
    float bv = __fadd_rn(__fadd_rn(__fmul_rn(F10, px), __fmul_rn(F11, py)), F12);
    float cv = __fadd_rn(__fadd_rn(__fmul_rn(F20, px), __fmul_rn(F21, py)), F22);

    bool horiz  = fabsf(bv) >= fabsf(av);
    float ncoef = horiz ? av : bv;
    float den   = __fmul_rn(horiz ? bv : av, d);
    float nrec  = -__fdiv_rn(1.0f, den);   // den 0/Inf/NaN -> u NaN -> masked

    const float4* P = cubes + (size_t)b * 32768 + (horiz ? 0 : 16384);

    // Conservative valid-k interval (exact per-step mask still applied).
    float A  = __fmul_rn(__fmul_rn(ncoef, d), nrec);
    float Bc = __fmul_rn(cv, nrec);
    int lkmin, lkmax;
    if (fabsf(A) > 1e-20f) {
        float inv = 1.0f / A;
        float k1 = (0.0f   - Bc) * inv;
        float k2 = (127.0f - Bc) * inv;
        float lo = fmaxf(fminf(k1, k2) - 2.0f, 0.0f);
        float hi = fminf(fmaxf(k1, k2) + 2.0f, 127.0f);
        if (lo > hi || !(lo == lo)) { lkmin = 1; lkmax = 0; }
        else { lkmin = (int)lo; lkmax = (int)hi; }
    } else {
        bool full = (Bc >= 0.0f) && (Bc <= 127.0f);
        lkmin = full ? 0 : 1;
        lkmax = full ? 127 : 0;
    }
    int wkmin = lkmin, wkmax = lkmax;
    #pragma unroll
    for (int off = 1; off < 64; off <<= 1) {
        wkmin = min(wkmin, __shfl_xor(wkmin, off));
        wkmax = max(wkmax, __shfl_xor(wkmax, off));
    }

    float a0 = 0.f, a1 = 0.f, a2 = 0.f, a3 = 0.f;
    int len = wkmax - wkmin + 1;
    if (len > 0) {
        int cnt = (len + 7) >> 3;
        int ks  = wkmin + seg * cnt;
        int ke  = min(ks + cnt - 1, wkmax);
        #pragma unroll 8
        for (int k = ks; k <= ke; ++k) {
            float m  = __fmul_rn((float)k, d);
            float q  = __fadd_rn(__fmul_rn(ncoef, m), cv);
            float u  = __fmul_rn(q, nrec);
            bool ok  = (u >= 0.f) && (u <= 127.f);
            int i0   = (int)floorf(u);            // NaN->0, sat; clamped next
            i0 = max(0, min(i0, 126));
            float w  = __fsub_rn(u, (float)i0);   // ==1 at u==127 -> row[127]
            h2 wp = __builtin_bit_cast(h2,
                        __builtin_amdgcn_cvt_pkrtz(__fsub_rn(1.f, w), w));
            wp = ok ? wp : (h2){(_Float16)0.f, (_Float16)0.f};
            float4 e = P[k * 128 + i0];
            a0 = __builtin_amdgcn_fdot2(wp, __builtin_bit_cast(h2, e.x), a0, false);
            a1 = __builtin_amdgcn_fdot2(wp, __builtin_bit_cast(h2, e.y), a1, false);
            a2 = __builtin_amdgcn_fdot2(wp, __builtin_bit_cast(h2, e.z), a2, false);
            a3 = __builtin_amdgcn_fdot2(wp, __builtin_bit_cast(h2, e.w), a3, false);
        }
    }

    __shared__ float part[8][4][64];
    part[seg][0][tx] = a0;
    part[seg][1][tx] = a1;
    part[seg][2][tx] = a2;
    part[seg][3][tx] = a3;
    __syncthreads();

    if (seg < 4) {                                // waves 0..3: one channel each
        int ch = seg;
        float s = part[0][ch][tx];
        #pragma unroll
        for (int t = 1; t < 8; ++t) s = __fadd_rn(s, part[t][ch][tx]);
        out[(((size_t)b * CC + ch) * HH + y) * WW + x] = s;
    }
}

extern "C" void kernel_launch(void* const* d_in, const int* in_sizes, int n_in,
                              void* d_out, int out_size, void* d_ws, size_t ws_size,
                              hipStream_t stream) {
    const float* view1 = (const float*)d_in[0];
    const float* F21   = (const float*)d_in[1];
    const float* dsf   = (const float*)d_in[3];

    const int B = in_sizes[3];

    dim3 stb(16, 16, 1);
    dim3 stg(WW / 16, HH / 16, B);
    fume_stage<<<stg, stb, 0, stream>>>(view1, (float4*)d_ws);

    dim3 ftb(64, 8, 1);
    dim3 ftg(WW / 8, HH / 8, B);
    fume_kernel<<<ftg, ftb, 0, stream>>>((const float4*)d_ws, F21, dsf,
                                         (float*)d_out);
}

// Round 11
// 67.158 us; speedup vs baseline: 1.0559x; 1.0559x over previous
//
#include <hip/hip_runtime.h>

// FUME epipolar translation, fp32 in/out. B from in_sizes[3]; C,H,W = 4,128,128.
//
// R11: R9 lane mapping (64x1 strip — R10's 8x8 tile regressed; fume is
// serial-work-bound, not line-transaction-bound) + per-lane k-intervals:
// each lane seg-splits its OWN conservative valid interval instead of the
// 64-lane wave union. Drops the 12-shfl union chain and cuts typical trip
// count ~2x (union ~128 vs median own-interval). Exec-mask divergence in k
// is free given R10's evidence. Per-step math bit-identical to R9; only
// seg partition boundaries move (k-ascending groups, fixed seg sum order).
//
// Workspace (16B entries = {half2(v[ch][u],v[ch][u+1])}ch=0..3):
//   horiz cube at entry ofs b*32768:        row r=x, col u=y : taps img[ch][u][x], img[ch][u+1][x]
//   vert  cube at entry ofs b*32768+16384:  row r=y, col u=x : taps img[ch][r][u], img[ch][r][u+1]
// (tap u+1 clamped at the image edge; entry col 127 is never read: i0<=126.)

#define CC 4
#define HH 128
#define WW 128

typedef _Float16 h2 __attribute__((ext_vector_type(2)));

__global__ void __launch_bounds__(256) fume_stage(
        const float* __restrict__ img, float4* __restrict__ ws) {
    __shared__ float tile[4][17][17];
    int x0 = blockIdx.x * 16, y0 = blockIdx.y * 16, b = blockIdx.z;
    int tx = threadIdx.x, ty = threadIdx.y;   // 16x16
    int id = ty * 16 + tx;
    const float* src = img + (size_t)b * CC * HH * WW;

    #pragma unroll
    for (int ch = 0; ch < 4; ++ch) {
        #pragma unroll
        for (int e = 0; e < 2; ++e) {
            int idx = id + e * 256;
            if (idx < 289) {
                int i = idx / 17, j = idx % 17;
                int r = min(y0 + i, HH - 1);
                int c = min(x0 + j, WW - 1);
                tile[ch][i][j] = src[(ch * HH + r) * WW + c];
            }
        }
    }
    __syncthreads();

    float4* base_h = ws + (size_t)b * 32768;
    float4* base_v = base_h + 16384;

    // vert entry: k = y0+ty, u = x0+tx : taps tile[ch][ty][tx], tile[ch][ty][tx+1]
    {
        h2 p0 = { (_Float16)tile[0][ty][tx], (_Float16)tile[0][ty][tx + 1] };
        h2 p1 = { (_Float16)tile[1][ty][tx], (_Float16)tile[1][ty][tx + 1] };
        h2 p2 = { (_Float16)tile[2][ty][tx], (_Float16)tile[2][ty][tx + 1] };
        h2 p3 = { (_Float16)tile[3][ty][tx], (_Float16)tile[3][ty][tx + 1] };
        float4 e = make_float4(__builtin_bit_cast(float, p0),
                               __builtin_bit_cast(float, p1),
                               __builtin_bit_cast(float, p2),
                               __builtin_bit_cast(float, p3));
        base_v[(y0 + ty) * WW + (x0 + tx)] = e;
    }
    // horiz entry: r = x0+ty, u = y0+tx : taps tile[ch][tx][ty], tile[ch][tx+1][ty]
    {
        h2 p0 = { (_Float16)tile[0][tx][ty], (_Float16)tile[0][tx + 1][ty] };
        h2 p1 = { (_Float16)tile[1][tx][ty], (_Float16)tile[1][tx + 1][ty] };
        h2 p2 = { (_Float16)tile[2][tx][ty], (_Float16)tile[2][tx + 1][ty] };
        h2 p3 = { (_Float16)tile[3][tx][ty], (_Float16)tile[3][tx + 1][ty] };
        float4 e = make_float4(__builtin_bit_cast(float, p0),
                               __builtin_bit_cast(float, p1),
                               __builtin_bit_cast(float, p2),
                               __builtin_bit_cast(float, p3));
        base_h[(x0 + ty) * HH + (y0 + tx)] = e;
    }
}

__global__ void __launch_bounds__(512) fume_kernel(
        const float4* __restrict__ cubes,
        const float* __restrict__ F,
        const float* __restrict__ dsf,
        float* __restrict__ out) {
    int tx  = threadIdx.x;               // 0..63 : x within group (one wave)
    int seg = threadIdx.y;               // 0..7  : k-segment (wave id)
    int x = blockIdx.x * 64 + tx;
    int y = blockIdx.y;
    int b = blockIdx.z;

    float d = dsf[b];
    float F00 = F[0], F01 = F[1], F02 = F[2];
    float F10 = F[3], F11 = F[4], F12 = F[5];
    float F20 = F[6], F21 = F[7], F22 = F[8];

    // Exact reference op order (no fma contraction).
    float px = __fmul_rn((float)x, d);
    float py = __fmul_rn((float)y, d);
    float av = __fadd_rn(__fadd_rn(__fmul_rn(F00, px), __fmul_rn(F01, py)), F02);
    float bv = __fadd_rn(__fadd_rn(__fmul_rn(F10, px), __fmul_rn(F11, py)), F12);
    float cv = __fadd_rn(__fadd_rn(__fmul_rn(F20, px), __fmul_rn(F21, py)), F22);

    bool horiz  = fabsf(bv) >= fabsf(av);
    float ncoef = horiz ? av : bv;
    float den   = __fmul_rn(horiz ? bv : av, d);
    float nrec  = -__fdiv_rn(1.0f, den);   // den 0/Inf/NaN -> u NaN -> masked

    const float4* P = cubes + (size_t)b * 32768 + (horiz ? 0 : 16384);

    // Conservative valid-k interval, PER LANE (exact mask still applied).
    float A  = __fmul_rn(__fmul_rn(ncoef, d), nrec);
    float Bc = __fmul_rn(cv, nrec);
    int lkmin, lkmax;
    if (fabsf(A) > 1e-20f) {
        float inv = 1.0f / A;
        float k1 = (0.0f   - Bc) * inv;
        float k2 = (127.0f - Bc) * inv;
        float lo = fmaxf(fminf(k1, k2) - 2.0f, 0.0f);
        float hi = fminf(fmaxf(k1, k2) + 2.0f, 127.0f);
        if (lo > hi || !(lo == lo)) { lkmin = 1; lkmax = 0; }
        else { lkmin = (int)lo; lkmax = (int)hi; }
    } else {
        bool full = (Bc >= 0.0f) && (Bc <= 127.0f);
        lkmin = full ? 0 : 1;
        lkmax = full ? 127 : 0;
    }

    float a0 = 0.f, a1 = 0.f, a2 = 0.f, a3 = 0.f;
    int len = lkmax - lkmin + 1;          // may be <=0 (empty)
    int cnt = (len + 7) >> 3;             // steps per seg for THIS lane
    int ks  = lkmin + seg * cnt;
    int ke  = min(ks + cnt - 1, lkmax);   // empty if len<=0
    #pragma unroll 8
    for (int k = ks; k <= ke; ++k) {
        float m  = __fmul_rn((float)k, d);
        float q  = __fadd_rn(__fmul_rn(ncoef, m), cv);
        float u  = __fmul_rn(q, nrec);
        bool ok  = (u >= 0.f) && (u <= 127.f);
        int i0   = (int)floorf(u);        // NaN->0, sat; clamped next
        i0 = max(0, min(i0, 126));
        float w  = __fsub_rn(u, (float)i0);   // ==1 at u==127 -> row[127]
        h2 wp = __builtin_bit_cast(h2,
                    __builtin_amdgcn_cvt_pkrtz(__fsub_rn(1.f, w), w));
        wp = ok ? wp : (h2){(_Float16)0.f, (_Float16)0.f};
        float4 e = P[k * 128 + i0];
        a0 = __builtin_amdgcn_fdot2(wp, __builtin_bit_cast(h2, e.x), a0, false);
        a1 = __builtin_amdgcn_fdot2(wp, __builtin_bit_cast(h2, e.y), a1, false);
        a2 = __builtin_amdgcn_fdot2(wp, __builtin_bit_cast(h2, e.z), a2, false);
        a3 = __builtin_amdgcn_fdot2(wp, __builtin_bit_cast(h2, e.w), a3, false);
    }

    __shared__ float part[8][4][64];
    part[seg][0][tx] = a0;
    part[seg][1][tx] = a1;
    part[seg][2][tx] = a2;
    part[seg][3][tx] = a3;
    __syncthreads();

    if (seg < 4) {                                // waves 0..3: one channel each
        int ch = seg;
        float s = part[0][ch][tx];
        #pragma unroll
        for (int t = 1; t < 8; ++t) s = __fadd_rn(s, part[t][ch][tx]);
        out[(((size_t)b * CC + ch) * HH + y) * WW + x] = s;
    }
}

extern "C" void kernel_launch(void* const* d_in, const int* in_sizes, int n_in,
                              void* d_out, int out_size, void* d_ws, size_t ws_size,
                              hipStream_t stream) {
    const float* view1 = (const float*)d_in[0];
    const float* F21   = (const float*)d_in[1];
    const float* dsf   = (const float*)d_in[3];

    const int B = in_sizes[3];

    dim3 stb(16, 16, 1);
    dim3 stg(WW / 16, HH / 16, B);
    fume_stage<<<stg, stb, 0, stream>>>(view1, (float4*)d_ws);

    dim3 ftb(64, 8, 1);
    dim3 ftg(WW / 64, HH, B);
    fume_kernel<<<ftg, ftb, 0, stream>>>((const float4*)d_ws, F21, dsf,
                                         (float*)d_out);
}